// Round 4
// baseline (125.659 us; speedup 1.0000x reference)
//
#include <hip/hip_runtime.h>
#include <stdint.h>

// inputs [B=64, T=256, D=1024] f32; tanh -> sequential dual-threshold
// integrate-and-fire scan over T per (b,d). 65536 sequences = 1024 waves
// = 1 wave/SIMD on 256 CUs (structural; scan is hysteretic, not
// prefix-decomposable).
//
// Round-4 theory: per-wave in-flight bytes were instruction-width-limited
// (vmcnt cap counts INSTRUCTIONS; 63 x 256B dword ops = 16KB/wave ->
// ~3.3 TB/s). The poison-fill kernel proves <1 wave/SIMD reaches 6.4 TB/s
// with wide ops and no waits. Fix: dwordx4 everywhere (1KB/wave/instr),
// LDS-transposed so each thread still owns one sequence:
//   load: lane L fetches t-row (L>>4), d-quad 4*(L&15) of a 16t x 64d
//         chunk tile -> ds_write_b128 at byte 16*L (+1024*m) == row-major
//         [16][64] f32 tile (exact identity, verified by construction).
//   consume: lane j reads tile[t][j] (ds_read_b32, 2-way bank alias=free).
//   store: symmetric transpose back, global_store_dwordx4.
// Per chunk: 4 loads + 4 stores (was 32 ops) -> LEAD=6 chunks of loads in
// flight = 24KB/wave = 24MB GPU-wide. Waves independent; no barriers.
#define B_DIM 64
#define T_STEPS 256
#define D_DIM 1024
#define CT 16                   // timesteps per chunk
#define CHUNKS (T_STEPS / CT)   // 16
#define TPB 256
// LEAD = 6 chunks; steady wait = 4*(2*LEAD-1) = 44 (loads+stores in order)

typedef float f32x4 __attribute__((ext_vector_type(4)));

// XLA/Eigen f32 tanh rational approximation — bit-exact vs jnp.tanh
// (verified: absmax = 0.0). DO NOT change the FMA structure.
__device__ __forceinline__ float xla_tanhf(float x) {
    const float kClamp = 7.90531110763549805f;
    float xc = fminf(fmaxf(x, -kClamp), kClamp);
    float x2 = xc * xc;
    float p = __builtin_fmaf(x2, -2.76076847742355e-16f, 2.00018790482477e-13f);
    p = __builtin_fmaf(x2, p, -8.60467152213735e-11f);
    p = __builtin_fmaf(x2, p, 5.12229709037114e-08f);
    p = __builtin_fmaf(x2, p, 1.48572235717979e-05f);
    p = __builtin_fmaf(x2, p, 6.37261928875436e-04f);
    p = __builtin_fmaf(x2, p, 4.89352455891786e-03f);
    p = xc * p;
    float q = __builtin_fmaf(x2, 1.19825839466702e-06f, 1.18534705686654e-04f);
    q = __builtin_fmaf(x2, q, 2.26843463243900e-03f);
    q = __builtin_fmaf(x2, q, 4.89352518554385e-03f);
    float r = p / q;           // IEEE divide — required for bit-exactness
    return (fabsf(x) < 0.0004f) ? x : r;
}

// Issue one chunk's 4 x4-loads into staging set {Q0..Q3}; each instr
// covers 4 t-rows x 64 d = 1KB; voffi advances 4 rows = 0x4000 per instr.
#define ISSUE4(Q0,Q1,Q2,Q3) asm volatile( \
    "global_load_dwordx4 %0, %4, %5\n\t" \
    "v_add_u32 %4, 0x4000, %4\n\t" \
    "global_load_dwordx4 %1, %4, %5\n\t" \
    "v_add_u32 %4, 0x4000, %4\n\t" \
    "global_load_dwordx4 %2, %4, %5\n\t" \
    "v_add_u32 %4, 0x4000, %4\n\t" \
    "global_load_dwordx4 %3, %4, %5\n\t" \
    "v_add_u32 %4, 0x4000, %4\n\t" \
    : "=v"(Q0), "=v"(Q1), "=v"(Q2), "=v"(Q3), "+v"(voffi) \
    : "s"(inp_u) : "memory")

// Wait until <= CNT vmem ops outstanding; "+v" on the staging set makes
// the following ds_writes data-dependent on this wait. vmcnt retires in
// order: outstanding<=N => everything older than newest N completed.
#define WAITVM(CNT, Q0,Q1,Q2,Q3) asm volatile("s_waitcnt vmcnt(" CNT ")" \
    : "+v"(Q0), "+v"(Q1), "+v"(Q2), "+v"(Q3) :: "memory")

// Stage set -> LDS in-tile (row-major [16][64] by construction).
#define STAGEW(Q0,Q1,Q2,Q3) asm volatile( \
    "ds_write_b128 %4, %0\n\t" \
    "ds_write_b128 %4, %1 offset:1024\n\t" \
    "ds_write_b128 %4, %2 offset:2048\n\t" \
    "ds_write_b128 %4, %3 offset:3072\n\t" \
    "s_waitcnt lgkmcnt(0)" \
    :: "v"(Q0), "v"(Q1), "v"(Q2), "v"(Q3), "v"(lin_w) : "memory")

// Per-lane column reads: x_t = tile[t][lane].
#define READ16() asm volatile( \
    "ds_read_b32 %0, %16\n\t" \
    "ds_read_b32 %1, %16 offset:256\n\t" \
    "ds_read_b32 %2, %16 offset:512\n\t" \
    "ds_read_b32 %3, %16 offset:768\n\t" \
    "ds_read_b32 %4, %16 offset:1024\n\t" \
    "ds_read_b32 %5, %16 offset:1280\n\t" \
    "ds_read_b32 %6, %16 offset:1536\n\t" \
    "ds_read_b32 %7, %16 offset:1792\n\t" \
    "ds_read_b32 %8, %16 offset:2048\n\t" \
    "ds_read_b32 %9, %16 offset:2304\n\t" \
    "ds_read_b32 %10, %16 offset:2560\n\t" \
    "ds_read_b32 %11, %16 offset:2816\n\t" \
    "ds_read_b32 %12, %16 offset:3072\n\t" \
    "ds_read_b32 %13, %16 offset:3328\n\t" \
    "ds_read_b32 %14, %16 offset:3584\n\t" \
    "ds_read_b32 %15, %16 offset:3840\n\t" \
    "s_waitcnt lgkmcnt(0)" \
    : "=v"(x0), "=v"(x1), "=v"(x2), "=v"(x3), \
      "=v"(x4), "=v"(x5), "=v"(x6), "=v"(x7), \
      "=v"(x8), "=v"(x9), "=v"(x10), "=v"(x11), \
      "=v"(x12), "=v"(x13), "=v"(x14), "=v"(x15) \
    : "v"(lin_r) : "memory")

// One scan step (bit-exact order preserved from the verified kernel).
#define STEP1(X, O) { \
    float r = xla_tanhf(X); \
    v = __builtin_fmaf(r, 0.01f, v); \
    float sp = (v >= 1.0f)  ? 1.0f : 0.0f; \
    float sn = (v <= -1.0f) ? 1.0f : 0.0f; \
    v = (v - sp) + sn; \
    O = (sp - sn) * 100.0f; }

#define COMP16() \
    STEP1(x0,o0)  STEP1(x1,o1)  STEP1(x2,o2)  STEP1(x3,o3) \
    STEP1(x4,o4)  STEP1(x5,o5)  STEP1(x6,o6)  STEP1(x7,o7) \
    STEP1(x8,o8)  STEP1(x9,o9)  STEP1(x10,o10) STEP1(x11,o11) \
    STEP1(x12,o12) STEP1(x13,o13) STEP1(x14,o14) STEP1(x15,o15)

// Out-tile column writes: tile[t][lane] = o_t.
#define OUTW16() asm volatile( \
    "ds_write_b32 %16, %0\n\t" \
    "ds_write_b32 %16, %1 offset:256\n\t" \
    "ds_write_b32 %16, %2 offset:512\n\t" \
    "ds_write_b32 %16, %3 offset:768\n\t" \
    "ds_write_b32 %16, %4 offset:1024\n\t" \
    "ds_write_b32 %16, %5 offset:1280\n\t" \
    "ds_write_b32 %16, %6 offset:1536\n\t" \
    "ds_write_b32 %16, %7 offset:1792\n\t" \
    "ds_write_b32 %16, %8 offset:2048\n\t" \
    "ds_write_b32 %16, %9 offset:2304\n\t" \
    "ds_write_b32 %16, %10 offset:2560\n\t" \
    "ds_write_b32 %16, %11 offset:2816\n\t" \
    "ds_write_b32 %16, %12 offset:3072\n\t" \
    "ds_write_b32 %16, %13 offset:3328\n\t" \
    "ds_write_b32 %16, %14 offset:3584\n\t" \
    "ds_write_b32 %16, %15 offset:3840\n\t" \
    "s_waitcnt lgkmcnt(0)" \
    :: "v"(o0), "v"(o1), "v"(o2), "v"(o3), \
       "v"(o4), "v"(o5), "v"(o6), "v"(o7), \
       "v"(o8), "v"(o9), "v"(o10), "v"(o11), \
       "v"(o12), "v"(o13), "v"(o14), "v"(o15), "v"(lout_w) : "memory")

// Transpose back (linear b128 gather) + 4 x4-stores.
#define GATHER_STORE() do { \
    f32x4 G0, G1, G2, G3; \
    asm volatile( \
        "ds_read_b128 %0, %4\n\t" \
        "ds_read_b128 %1, %4 offset:1024\n\t" \
        "ds_read_b128 %2, %4 offset:2048\n\t" \
        "ds_read_b128 %3, %4 offset:3072\n\t" \
        "s_waitcnt lgkmcnt(0)" \
        : "=v"(G0), "=v"(G1), "=v"(G2), "=v"(G3) : "v"(lout_r) : "memory"); \
    asm volatile( \
        "global_store_dwordx4 %0, %1, %5\n\t" \
        "v_add_u32 %0, 0x4000, %0\n\t" \
        "global_store_dwordx4 %0, %2, %5\n\t" \
        "v_add_u32 %0, 0x4000, %0\n\t" \
        "global_store_dwordx4 %0, %3, %5\n\t" \
        "v_add_u32 %0, 0x4000, %0\n\t" \
        "global_store_dwordx4 %0, %4, %5\n\t" \
        "v_add_u32 %0, 0x4000, %0\n\t" \
        : "+v"(voffo) : "v"(G0), "v"(G1), "v"(G2), "v"(G3), "s"(outp_u) \
        : "memory"); } while (0)

// Chunk with re-issue (chunks 0..9): consume set, reload it for c+LEAD.
#define CHUNK_I(NSTR, Q0,Q1,Q2,Q3) do { \
    float x0,x1,x2,x3,x4,x5,x6,x7,x8,x9,x10,x11,x12,x13,x14,x15; \
    float o0,o1,o2,o3,o4,o5,o6,o7,o8,o9,o10,o11,o12,o13,o14,o15; \
    WAITVM(NSTR, Q0,Q1,Q2,Q3); \
    STAGEW(Q0,Q1,Q2,Q3); \
    ISSUE4(Q0,Q1,Q2,Q3); \
    READ16(); COMP16(); OUTW16(); GATHER_STORE(); } while (0)

// Tail chunk (10..15): no more loads to issue.
#define CHUNK_N(NSTR, Q0,Q1,Q2,Q3) do { \
    float x0,x1,x2,x3,x4,x5,x6,x7,x8,x9,x10,x11,x12,x13,x14,x15; \
    float o0,o1,o2,o3,o4,o5,o6,o7,o8,o9,o10,o11,o12,o13,o14,o15; \
    WAITVM(NSTR, Q0,Q1,Q2,Q3); \
    STAGEW(Q0,Q1,Q2,Q3); \
    READ16(); COMP16(); OUTW16(); GATHER_STORE(); } while (0)

__global__ __launch_bounds__(TPB)
void spike_scan_kernel(const float* __restrict__ in, float* __restrict__ out) {
    __shared__ __align__(16) float lds_in[4][CT * 64];    // 4KB per wave
    __shared__ __align__(16) float lds_out[4][CT * 64];   // 4KB per wave

    const int widx = threadIdx.x >> 6;       // wave in block (0..3)
    const int lane = threadIdx.x & 63;
    const int w = blockIdx.x * 4 + widx;     // global wave 0..1023
    const int b = w >> 4;                    // 16 waves per b (16*64 d)
    const int dbase = (w & 15) << 6;         // wave's d range [dbase, dbase+64)

    // Per-lane quarter-wave x4 addressing: t-row (lane>>4), d-quad 4*(lane&15).
    uint32_t base = (uint32_t)b * (T_STEPS * D_DIM * 4u)
                  + (uint32_t)(lane >> 4) * (D_DIM * 4u)
                  + ((uint32_t)dbase + 4u * (uint32_t)(lane & 15)) * 4u;
    uint32_t voffi = base;
    uint32_t voffo = base;
    const uint64_t inp_u  = (uint64_t)in;
    const uint64_t outp_u = (uint64_t)out;

    // LDS byte addresses (generic LDS pointer low 32 bits = LDS offset).
    const uint32_t lin_base  = (uint32_t)(uintptr_t)&lds_in[widx][0];
    const uint32_t lout_base = (uint32_t)(uintptr_t)&lds_out[widx][0];
    const uint32_t lin_w  = lin_base  + 16u * (uint32_t)lane;  // b128 stage
    const uint32_t lin_r  = lin_base  +  4u * (uint32_t)lane;  // b32 column
    const uint32_t lout_w = lout_base +  4u * (uint32_t)lane;  // b32 column
    const uint32_t lout_r = lout_base + 16u * (uint32_t)lane;  // b128 gather

    f32x4 a0,a1,a2,a3, b0,b1,b2,b3, c0,c1,c2,c3,
          d0,d1,d2,d3, e0,e1,e2,e3, f0,f1,f2,f3;   // 6 staging sets (LEAD)
    float v = 0.0f;

    // Prologue: L0..L5 in flight (24 instrs, 24KB/wave).
    ISSUE4(a0,a1,a2,a3); ISSUE4(b0,b1,b2,b3); ISSUE4(c0,c1,c2,c3);
    ISSUE4(d0,d1,d2,d3); ISSUE4(e0,e1,e2,e3); ISSUE4(f0,f1,f2,f3);

    // Wait N at chunk c: loads newer than L(c) = 4*min(5,15-c),
    // stores newer = 4*min(c,6)  (S(y) issued end of chunk y, L(c) issued
    // in chunk c-6 / prologue). Steady state N=44.
    CHUNK_I("20", a0,a1,a2,a3);   // c0  (issues L6)
    CHUNK_I("24", b0,b1,b2,b3);   // c1
    CHUNK_I("28", c0,c1,c2,c3);   // c2
    CHUNK_I("32", d0,d1,d2,d3);   // c3
    CHUNK_I("36", e0,e1,e2,e3);   // c4
    CHUNK_I("40", f0,f1,f2,f3);   // c5
    CHUNK_I("44", a0,a1,a2,a3);   // c6  (issues L12)
    CHUNK_I("44", b0,b1,b2,b3);   // c7
    CHUNK_I("44", c0,c1,c2,c3);   // c8
    CHUNK_I("44", d0,d1,d2,d3);   // c9  (issues L15)
    CHUNK_N("44", e0,e1,e2,e3);   // c10
    CHUNK_N("40", f0,f1,f2,f3);   // c11
    CHUNK_N("36", a0,a1,a2,a3);   // c12
    CHUNK_N("32", b0,b1,b2,b3);   // c13
    CHUNK_N("28", c0,c1,c2,c3);   // c14
    CHUNK_N("24", d0,d1,d2,d3);   // c15
}

extern "C" void kernel_launch(void* const* d_in, const int* in_sizes, int n_in,
                              void* d_out, int out_size, void* d_ws, size_t ws_size,
                              hipStream_t stream) {
    const float* in = (const float*)d_in[0];
    float* out = (float*)d_out;
    dim3 block(TPB);
    dim3 grid((B_DIM * D_DIM) / TPB);    // 256 blocks = 1024 waves, 1/SIMD
    spike_scan_kernel<<<grid, block, 0, stream>>>(in, out);
}

// Round 5
// 109.619 us; speedup vs baseline: 1.1463x; 1.1463x over previous
//
#include <hip/hip_runtime.h>
#include <stdint.h>

// inputs [B=64, T=256, D=1024] f32; tanh -> sequential dual-threshold
// integrate-and-fire scan over T per (b,d).
//
// Round-5 structure: intra-block T-pipeline. The scan is hysteretic (not
// prefix-decomposable), but only the 9-op v-chain is sequential — loads
// and tanh() are not. Block = 4 waves over the SAME 64 sequences; wave k
// owns timesteps [64k,64k+64). All waves load + tanh in parallel (4096
// waves total = 16/CU = 4/SIMD occupancy, vs 1/SIMD before — this is the
// TLP that rounds 0-4 proved was missing: per-wave MLP levers were all
// null while VALUBusy sat at 27% and BW at 2 TB/s). The v-state hops
// wave->wave via LDS + acquire/release flag; serial chain per block =
// 4 x ~0.5us scan instead of 4 x ~3.2us tanh+scan. Intra-block sync only
// -> co-residency guaranteed, no deadlock, no XCD coherence exposure.
#define B_DIM 64
#define T_STEPS 256
#define D_DIM 1024
#define TPB 256
#define SEQ_PER_BLK 64          // one wave-width of sequences per block
#define TQ 64                   // timesteps per wave (T/4)

// XLA/Eigen f32 tanh rational approximation — bit-exact vs jnp.tanh
// (verified: absmax = 0.0). DO NOT change the FMA structure.
__device__ __forceinline__ float xla_tanhf(float x) {
    const float kClamp = 7.90531110763549805f;
    float xc = fminf(fmaxf(x, -kClamp), kClamp);
    float x2 = xc * xc;
    float p = __builtin_fmaf(x2, -2.76076847742355e-16f, 2.00018790482477e-13f);
    p = __builtin_fmaf(x2, p, -8.60467152213735e-11f);
    p = __builtin_fmaf(x2, p, 5.12229709037114e-08f);
    p = __builtin_fmaf(x2, p, 1.48572235717979e-05f);
    p = __builtin_fmaf(x2, p, 6.37261928875436e-04f);
    p = __builtin_fmaf(x2, p, 4.89352455891786e-03f);
    p = xc * p;
    float q = __builtin_fmaf(x2, 1.19825839466702e-06f, 1.18534705686654e-04f);
    q = __builtin_fmaf(x2, q, 2.26843463243900e-03f);
    q = __builtin_fmaf(x2, q, 4.89352518554385e-03f);
    float r = p / q;           // IEEE divide — required for bit-exactness
    return (fabsf(x) < 0.0004f) ? x : r;
}

// --- raw-asm building blocks (proven structure from rounds 1-4) ----------
// One load + advance voff by one timestep (D_DIM*4 = 4096 B). saddr form:
// addr = SGPR base + zext(voff); tensor is 64 MB so 32-bit offsets fit.
#define LD(i) "global_load_dword %" #i ", %16, %17\n\t" \
              "v_add_u32 %16, 0x1000, %16\n\t"

// Issue 16 loads into 16-reg slice B; compiler never sees them as memory
// ops -> no auto-waitcnt; vmcnt tracked manually.
#define ISSUE16(B) asm volatile( \
    LD(0) LD(1) LD(2) LD(3) LD(4) LD(5) LD(6) LD(7) \
    LD(8) LD(9) LD(10) LD(11) LD(12) LD(13) LD(14) LD(15) \
    : "=v"(B[0]), "=v"(B[1]), "=v"(B[2]), "=v"(B[3]), \
      "=v"(B[4]), "=v"(B[5]), "=v"(B[6]), "=v"(B[7]), \
      "=v"(B[8]), "=v"(B[9]), "=v"(B[10]), "=v"(B[11]), \
      "=v"(B[12]), "=v"(B[13]), "=v"(B[14]), "=v"(B[15]), \
      "+v"(voffi) \
    : "s"(inp_u) : "memory")

// Wait until <= CNT vmem ops outstanding; "+v" on the slice makes every
// use data-dependent on this wait. Only loads are in the queue during the
// tanh phase (all stores happen after), so vmcnt(0) at the tail is safe.
#define WAITBUF(B, CNT) asm volatile("s_waitcnt vmcnt(" CNT ")" \
    : "+v"(B[0]), "+v"(B[1]), "+v"(B[2]), "+v"(B[3]), \
      "+v"(B[4]), "+v"(B[5]), "+v"(B[6]), "+v"(B[7]), \
      "+v"(B[8]), "+v"(B[9]), "+v"(B[10]), "+v"(B[11]), \
      "+v"(B[12]), "+v"(B[13]), "+v"(B[14]), "+v"(B[15]) \
    :: "memory")

// Opaque keep-alive: pins the tanh results as "computed here" so the
// compiler cannot sink the tanh chains below the (volatile) spin loop —
// asm volatile blocks are not reordered across atomic ops.
#define KEEP16(B) asm volatile("" \
    : "+v"(B[0]), "+v"(B[1]), "+v"(B[2]), "+v"(B[3]), \
      "+v"(B[4]), "+v"(B[5]), "+v"(B[6]), "+v"(B[7]), \
      "+v"(B[8]), "+v"(B[9]), "+v"(B[10]), "+v"(B[11]), \
      "+v"(B[12]), "+v"(B[13]), "+v"(B[14]), "+v"(B[15]))

#define TANH16(B) do { \
    _Pragma("unroll") \
    for (int u = 0; u < 16; ++u) B[u] = xla_tanhf(B[u]); \
    KEEP16(B); } while (0)

// Scan 16 steps in place: consumes tanh value B[u], leaves output in B[u].
// Bit-exact op order preserved from the verified kernel: the *0.01 stays
// fused in the fma (precomputing r*DT would change rounding).
#define SCAN16(B) do { \
    _Pragma("unroll") \
    for (int u = 0; u < 16; ++u) { \
        float r = B[u]; \
        v = __builtin_fmaf(r, 0.01f, v); \
        float sp = (v >= 1.0f)  ? 1.0f : 0.0f; \
        float sn = (v <= -1.0f) ? 1.0f : 0.0f; \
        v = (v - sp) + sn; \
        B[u] = (sp - sn) * 100.0f; \
    } } while (0)

// 16 nontemporal stores (after handoff — nothing ever waits on vmcnt
// again, so store retire latency is fully off the critical path; nt keeps
// the output stream from evicting the L3-resident input).
#define STORE16(B) asm volatile( \
    "global_store_dword %16, %0, %17 nt\n\t"  "v_add_u32 %16, 0x1000, %16\n\t" \
    "global_store_dword %16, %1, %17 nt\n\t"  "v_add_u32 %16, 0x1000, %16\n\t" \
    "global_store_dword %16, %2, %17 nt\n\t"  "v_add_u32 %16, 0x1000, %16\n\t" \
    "global_store_dword %16, %3, %17 nt\n\t"  "v_add_u32 %16, 0x1000, %16\n\t" \
    "global_store_dword %16, %4, %17 nt\n\t"  "v_add_u32 %16, 0x1000, %16\n\t" \
    "global_store_dword %16, %5, %17 nt\n\t"  "v_add_u32 %16, 0x1000, %16\n\t" \
    "global_store_dword %16, %6, %17 nt\n\t"  "v_add_u32 %16, 0x1000, %16\n\t" \
    "global_store_dword %16, %7, %17 nt\n\t"  "v_add_u32 %16, 0x1000, %16\n\t" \
    "global_store_dword %16, %8, %17 nt\n\t"  "v_add_u32 %16, 0x1000, %16\n\t" \
    "global_store_dword %16, %9, %17 nt\n\t"  "v_add_u32 %16, 0x1000, %16\n\t" \
    "global_store_dword %16, %10, %17 nt\n\t" "v_add_u32 %16, 0x1000, %16\n\t" \
    "global_store_dword %16, %11, %17 nt\n\t" "v_add_u32 %16, 0x1000, %16\n\t" \
    "global_store_dword %16, %12, %17 nt\n\t" "v_add_u32 %16, 0x1000, %16\n\t" \
    "global_store_dword %16, %13, %17 nt\n\t" "v_add_u32 %16, 0x1000, %16\n\t" \
    "global_store_dword %16, %14, %17 nt\n\t" "v_add_u32 %16, 0x1000, %16\n\t" \
    "global_store_dword %16, %15, %17 nt\n\t" "v_add_u32 %16, 0x1000, %16\n\t" \
    :: "v"(B[0]), "v"(B[1]), "v"(B[2]), "v"(B[3]), \
       "v"(B[4]), "v"(B[5]), "v"(B[6]), "v"(B[7]), \
       "v"(B[8]), "v"(B[9]), "v"(B[10]), "v"(B[11]), \
       "v"(B[12]), "v"(B[13]), "v"(B[14]), "v"(B[15]), \
       "v"(voffo), "s"(outp_u) : "memory")

__global__ __launch_bounds__(TPB)
void spike_scan_kernel(const float* __restrict__ in, float* __restrict__ out) {
    __shared__ float vstate[3][SEQ_PER_BLK];   // v handed stage k -> k+1
    __shared__ unsigned int flag[4];

    const int lane = threadIdx.x & 63;
    const int wk   = threadIdx.x >> 6;         // pipeline stage 0..3

    if (threadIdx.x < 4) flag[threadIdx.x] = 0u;
    __syncthreads();

    // Block handles 64 consecutive sequences; wave k handles their
    // timesteps [wk*64, wk*64+64). seq = blockIdx*64 + lane.
    const uint32_t sgrp  = (uint32_t)blockIdx.x << 6;
    const uint32_t b     = sgrp >> 10;               // batch index
    const uint32_t dbase = sgrp & (D_DIM - 1);       // d range base
    uint32_t voffi = b * (T_STEPS * D_DIM * 4u)
                   + (uint32_t)wk * (TQ * D_DIM * 4u)
                   + (dbase + (uint32_t)lane) * 4u;
    uint32_t voffo = voffi;
    const uint64_t inp_u  = (uint64_t)in;
    const uint64_t outp_u = (uint64_t)out;

    float rA[16], rB[16], rC[16], rD[16];      // this wave's 64 timesteps

    // Issue all 64 loads (cap-throttled past 63 outstanding — harmless),
    // then tanh each slice as it lands. All 4 waves do this in parallel.
    ISSUE16(rA); ISSUE16(rB); ISSUE16(rC); ISSUE16(rD);
    WAITBUF(rA, "48"); TANH16(rA);
    WAITBUF(rB, "32"); TANH16(rB);
    WAITBUF(rC, "16"); TANH16(rC);
    WAITBUF(rD, "0");  TANH16(rD);

    // --- serial section: only the 9-op v-chain, ~0.5us per stage ---
    float v = 0.0f;
    if (wk != 0) {
        while (__hip_atomic_load(&flag[wk - 1], __ATOMIC_ACQUIRE,
                                 __HIP_MEMORY_SCOPE_WORKGROUP) == 0u)
            __builtin_amdgcn_s_sleep(1);
        v = vstate[wk - 1][lane];
    }
    SCAN16(rA); SCAN16(rB); SCAN16(rC); SCAN16(rD);
    if (wk != 3) {
        vstate[wk][lane] = v;
        __hip_atomic_store(&flag[wk], 1u, __ATOMIC_RELEASE,
                           __HIP_MEMORY_SCOPE_WORKGROUP);
    }
    // --- end serial section; stores off the critical chain ---

    STORE16(rA); voffo += 16u * 0x1000u;
    STORE16(rB); voffo += 16u * 0x1000u;
    STORE16(rC); voffo += 16u * 0x1000u;
    STORE16(rD);
}

extern "C" void kernel_launch(void* const* d_in, const int* in_sizes, int n_in,
                              void* d_out, int out_size, void* d_ws, size_t ws_size,
                              hipStream_t stream) {
    const float* in = (const float*)d_in[0];
    float* out = (float*)d_out;
    dim3 block(TPB);
    dim3 grid((B_DIM * D_DIM) / SEQ_PER_BLK);   // 1024 blocks = 4096 waves
    spike_scan_kernel<<<grid, block, 0, stream>>>(in, out);
}